// Round 11
// baseline (604.009 us; speedup 1.0000x reference)
//
#include <hip/hip_runtime.h>
#include <hip/hip_cooperative_groups.h>
#include <hip/hip_fp16.h>
#include <math.h>

namespace cg = cooperative_groups;

#define N_PTS 50000
#define C_DIM 64
#define K_RAD 32
#define K_KNN 10
#define NTHREADS 256

// ROCm hip_fp16.h has no __hmax2; emit packed fp16 max directly.
__device__ inline __half2 hmax2(__half2 a, __half2 b) {
    __half2 d;
    asm("v_pk_max_f16 %0, %1, %2" : "=v"(d) : "v"(a), "v"(b));
    return d;
}

__device__ inline __half2 shfl_xor_h2(__half2 v, int mask) {
    int i = *(int*)&v;
    int r = __shfl_xor(i, mask);
    return *(__half2*)&r;
}

// ---- shared device bodies (identical math in fused + fallback paths) ----

__device__ __forceinline__ void pack_body(int i,
                                          const float* __restrict__ pos0,
                                          const float* __restrict__ x0,
                                          const int* __restrict__ assign,
                                          const float* __restrict__ R0,
                                          const float* __restrict__ t0,
                                          float4* __restrict__ geo,
                                          float4* __restrict__ rt4) {
    geo[i * 2 + 0] = make_float4(pos0[3 * i], pos0[3 * i + 1], pos0[3 * i + 2], x0[3 * i]);
    geo[i * 2 + 1] = make_float4(x0[3 * i + 1], x0[3 * i + 2], __int_as_float(assign[i]), 0.0f);
    const float* R = R0 + 9 * i;
    rt4[i * 4 + 0] = make_float4(R[0], R[1], R[2], R[3]);
    rt4[i * 4 + 1] = make_float4(R[4], R[5], R[6], R[7]);
    rt4[i * 4 + 2] = make_float4(R[8], t0[3 * i], t0[3 * i + 1], t0[3 * i + 2]);
}

// Phase-1 body: 16 nodes per block-iteration; needs lm[16][64], ldsR, ldsT.
__device__ __forceinline__ void ew_body(int blk, int tid,
                                        int (*lm)[C_DIM], float* ldsR, float* ldsT,
                                        const float4* __restrict__ geo,
                                        const float* __restrict__ R0,
                                        const float* __restrict__ t0,
                                        const int* __restrict__ radius_src,
                                        unsigned int* __restrict__ packed,
                                        __half* __restrict__ mA,
                                        float* __restrict__ sum1) {
    ((int*)lm)[tid] = 0;
    ((int*)lm)[tid + 256] = 0;
    ((int*)lm)[tid + 512] = 0;
    ((int*)lm)[tid + 768] = 0;
    if (tid < 144) ldsR[tid] = R0[blk * 144 + tid];
    if (tid < 48) ldsT[tid] = t0[blk * 48 + tid];
    int nl = tid >> 4;
    int ng = blk * 16 + nl;
    int e0 = tid & 15, e1 = e0 + 16;
    int s0 = radius_src[ng * K_RAD + e0];
    int s1 = radius_src[ng * K_RAD + e1];
    float4 g0a = geo[s0 * 2 + 0];
    float4 g0b = geo[s0 * 2 + 1];
    float4 g1a = geo[s1 * 2 + 0];
    float4 g1b = geo[s1 * 2 + 1];
    __syncthreads();
    const float* R = ldsR + nl * 9;
    const float* T = ldsT + nl * 3;
    float r0 = R[0] * g0a.x + R[1] * g0a.y + R[2] * g0a.z + T[0] - g0a.w;
    float r1 = R[3] * g0a.x + R[4] * g0a.y + R[5] * g0a.z + T[1] - g0b.x;
    float r2 = R[6] * g0a.x + R[7] * g0a.y + R[8] * g0a.z + T[2] - g0b.y;
    float d0 = r0 * r0 + r1 * r1 + r2 * r2;
    float w0 = 1.0f / (1.0f + __expf(d0 - 0.01f));
    float u0 = R[0] * g1a.x + R[1] * g1a.y + R[2] * g1a.z + T[0] - g1a.w;
    float u1 = R[3] * g1a.x + R[4] * g1a.y + R[5] * g1a.z + T[1] - g1b.x;
    float u2 = R[6] * g1a.x + R[7] * g1a.y + R[8] * g1a.z + T[2] - g1b.y;
    float d1 = u0 * u0 + u1 * u1 + u2 * u2;
    float w1 = 1.0f / (1.0f + __expf(d1 - 0.01f));
    packed[ng * K_RAD + e0] =
        ((unsigned int)s0 << 16) | (unsigned int)__half_as_ushort(__float2half_rn(w0));
    packed[ng * K_RAD + e1] =
        ((unsigned int)s1 << 16) | (unsigned int)__half_as_ushort(__float2half_rn(w1));
    atomicMax(&lm[nl][__float_as_int(g0b.z)], __float_as_int(w0));
    atomicMax(&lm[nl][__float_as_int(g1b.z)], __float_as_int(w1));
    __syncthreads();
    int c0 = (tid & 15) * 4;
    float v0 = __int_as_float(lm[nl][c0 + 0]);
    float v1 = __int_as_float(lm[nl][c0 + 1]);
    float v2 = __int_as_float(lm[nl][c0 + 2]);
    float v3 = __int_as_float(lm[nl][c0 + 3]);
    __half2 h01 = __floats2half2_rn(v0, v1);
    __half2 h23 = __floats2half2_rn(v2, v3);
    uint2 uo = make_uint2(*(unsigned int*)&h01, *(unsigned int*)&h23);
    *(uint2*)(mA + ng * C_DIM + c0) = uo;
    float s = v0 + v1 + v2 + v3;
    s += __shfl_down(s, 8);
    s += __shfl_down(s, 4);
    s += __shfl_down(s, 2);
    s += __shfl_down(s, 1);
    if ((tid & 15) == 0) sum1[ng] = s;
}

// Layer body: 2 nodes/wave, 8 independent 16B gathers; returns row sum.
__device__ __forceinline__ float layer_body(const unsigned int* __restrict__ packed,
                                            const __half* __restrict__ xin,
                                            __half* __restrict__ xout,
                                            int node, int lane, bool store) {
    int eslot = (lane >> 3) & 3;
    int cpos = lane & 7;
    const uint4* pk4 = (const uint4*)(packed + node * K_RAD + eslot * 8);
    uint4 q0 = pk4[0], q1 = pk4[1];
    unsigned int pes[8] = {q0.x, q0.y, q0.z, q0.w, q1.x, q1.y, q1.z, q1.w};
    __half2 a0 = __float2half2_rn(0.0f), a1 = a0, a2 = a0, a3 = a0;
#pragma unroll
    for (int p = 0; p < 8; ++p) {
        unsigned int pe = pes[p];
        float4 f = *(const float4*)(xin + (pe >> 16) * C_DIM + cpos * 8);
        __half2* h = (__half2*)&f;
        __half2 w2 = __half2half2(__ushort_as_half((unsigned short)(pe & 0xffffu)));
        a0 = hmax2(a0, __hmul2(w2, h[0]));
        a1 = hmax2(a1, __hmul2(w2, h[1]));
        a2 = hmax2(a2, __hmul2(w2, h[2]));
        a3 = hmax2(a3, __hmul2(w2, h[3]));
    }
#pragma unroll
    for (int off = 8; off <= 16; off <<= 1) {
        a0 = hmax2(a0, shfl_xor_h2(a0, off));
        a1 = hmax2(a1, shfl_xor_h2(a1, off));
        a2 = hmax2(a2, shfl_xor_h2(a2, off));
        a3 = hmax2(a3, shfl_xor_h2(a3, off));
    }
    if (store && eslot == 0) {
        float4 o;
        __half2* oh = (__half2*)&o;
        oh[0] = a0; oh[1] = a1; oh[2] = a2; oh[3] = a3;
        ((float4*)(xout + node * C_DIM))[cpos] = o;
    }
    float2 v0 = __half22float2(a0), v1 = __half22float2(a1);
    float2 v2 = __half22float2(a2), v3 = __half22float2(a3);
    float s = v0.x + v0.y + v1.x + v1.y + v2.x + v2.y + v3.x + v3.y;
    s += __shfl_xor(s, 1);
    s += __shfl_xor(s, 2);
    s += __shfl_xor(s, 4);
    return s;
}

__device__ __forceinline__ void wavg_body(int t, int lane,
                                          const int* __restrict__ knn_src,
                                          const float4* __restrict__ rt4,
                                          const float* __restrict__ pos0,
                                          float* __restrict__ out) {
    int part = lane & 3;
    float4 acc = make_float4(0.f, 0.f, 0.f, 0.f);
    for (int j = 0; j < K_KNN; ++j) {
        int s = knn_src[t * K_KNN + j];
        float4 q = rt4[s * 4 + part];      // part3: q.x = conf[s]
        float c = __shfl(q.x, lane | 3);
        if (part == 3) {
            acc.x += c;
        } else {
            acc.x += c * q.x; acc.y += c * q.y;
            acc.z += c * q.z; acc.w += c * q.w;
        }
    }
    float den = __shfl(acc.x, lane | 3) + 1e-8f;
    float inv = 1.0f / den;
    float4 sc = make_float4(acc.x * inv, acc.y * inv, acc.z * inv, acc.w * inv);
    int base = lane & ~3;
    float R3 = __shfl(sc.w, base + 0);
    float R6 = __shfl(sc.z, base + 1);
    float R7 = __shfl(sc.w, base + 1);
    float t0v = __shfl(sc.y, base + 2);
    float t1v = __shfl(sc.z, base + 2);
    float px = pos0[t * 3 + 0], py = pos0[t * 3 + 1], pz = pos0[t * 3 + 2];
    float* Rout = out + N_PTS * 3;
    float* tout = out + N_PTS * 12;
    if (part == 0) {
        out[t * 3 + 0] = sc.x * px + sc.y * py + sc.z * pz + t0v;
        Rout[t * 9 + 0] = sc.x; Rout[t * 9 + 1] = sc.y;
        Rout[t * 9 + 2] = sc.z; Rout[t * 9 + 3] = sc.w;
    } else if (part == 1) {
        out[t * 3 + 1] = R3 * px + sc.x * py + sc.y * pz + t1v;
        Rout[t * 9 + 4] = sc.x; Rout[t * 9 + 5] = sc.y;
        Rout[t * 9 + 6] = sc.z; Rout[t * 9 + 7] = sc.w;
    } else if (part == 2) {
        out[t * 3 + 2] = R6 * px + R7 * py + sc.x * pz + sc.w;
        Rout[t * 9 + 8] = sc.x;
        tout[t * 3 + 0] = sc.y; tout[t * 3 + 1] = sc.z; tout[t * 3 + 2] = sc.w;
    }
}

// ---------------- fused cooperative kernel (grid-size agnostic) ----------
__global__ __launch_bounds__(NTHREADS, 2) void fused_kernel(
    const float* __restrict__ x0, const float* __restrict__ pos0,
    const float* __restrict__ R0, const float* __restrict__ t0,
    const int* __restrict__ assign, const int* __restrict__ radius_src,
    const int* __restrict__ knn_src,
    unsigned int* __restrict__ packed, __half* __restrict__ mA,
    __half* __restrict__ mB, float4* __restrict__ geo,
    float4* __restrict__ rt4, float* __restrict__ sum1,
    float* __restrict__ sum2, float* __restrict__ out) {
    cg::grid_group grid = cg::this_grid();
    __shared__ int lm[16][C_DIM];
    __shared__ float ldsR[16 * 9];
    __shared__ float ldsT[16 * 3];
    int tid = threadIdx.x;
    int lane = tid & 63;
    int nblocks = gridDim.x;
    int nwaves = nblocks * (NTHREADS / 64);
    int gw = blockIdx.x * (NTHREADS / 64) + (tid >> 6);

    for (int i = blockIdx.x * NTHREADS + tid; i < N_PTS; i += nblocks * NTHREADS)
        pack_body(i, pos0, x0, assign, R0, t0, geo, rt4);
    grid.sync();

    for (int blk = blockIdx.x; blk < N_PTS / 16; blk += nblocks) {
        ew_body(blk, tid, lm, ldsR, ldsT, geo, R0, t0, radius_src, packed, mA, sum1);
        __syncthreads();
    }
    grid.sync();

    for (int task = gw; task < N_PTS / 2; task += nwaves) {
        int node = task * 2 + (lane >> 5);
        float s = layer_body(packed, mA, mB, node, lane, true);
        if ((lane & 31) == 0) sum2[node] = s;
    }
    grid.sync();

    for (int task = gw; task < N_PTS / 2; task += nwaves) {
        int node = task * 2 + (lane >> 5);
        float s = layer_body(packed, mB, (__half*)nullptr, node, lane, false);
        if ((lane & 31) == 0) {
            float tot = sum1[node] + sum2[node] + 3.0f * s - 17.0f;
            ((float*)rt4)[node * 16 + 12] = 1.0f / (1.0f + __expf(-tot));
        }
    }
    grid.sync();

    for (int task = gw; task < N_PTS / 16; task += nwaves)
        wavg_body(task * 16 + (lane >> 2), lane, knn_src, rt4, pos0, out);
}

// ---------------- fallback kernels (R9-verified path) ----------------
__global__ void pack_tables_kernel(const float* __restrict__ pos0,
                                   const float* __restrict__ x0,
                                   const int* __restrict__ assign,
                                   const float* __restrict__ R0,
                                   const float* __restrict__ t0,
                                   float4* __restrict__ geo,
                                   float4* __restrict__ rt4) {
    int i = blockIdx.x * blockDim.x + threadIdx.x;
    if (i >= N_PTS) return;
    pack_body(i, pos0, x0, assign, R0, t0, geo, rt4);
}

__global__ void ew_layer1_kernel(const float4* __restrict__ geo,
                                 const float* __restrict__ R0,
                                 const float* __restrict__ t0,
                                 const int* __restrict__ src,
                                 unsigned int* __restrict__ packed,
                                 __half* __restrict__ m1,
                                 float* __restrict__ sum1) {
    __shared__ int lm[16][C_DIM];
    __shared__ float ldsR[16 * 9];
    __shared__ float ldsT[16 * 3];
    ew_body(blockIdx.x, threadIdx.x, lm, ldsR, ldsT, geo, R0, t0, src, packed, m1, sum1);
}

__global__ void layer_pk_kernel(const unsigned int* __restrict__ packed,
                                const __half* __restrict__ xin,
                                __half* __restrict__ xout,
                                float* __restrict__ sum_out) {
    int gid = blockIdx.x * blockDim.x + threadIdx.x;
    int lane = gid & 63;
    int node = (gid >> 6) * 2 + (lane >> 5);
    float s = layer_body(packed, xin, xout, node, lane, true);
    if ((lane & 31) == 0) sum_out[node] = s;
}

__global__ void layer3_conf_pk_kernel(const unsigned int* __restrict__ packed,
                                      const __half* __restrict__ xin,
                                      const float* __restrict__ sum1,
                                      const float* __restrict__ sum2,
                                      float* __restrict__ rt4f) {
    int gid = blockIdx.x * blockDim.x + threadIdx.x;
    int lane = gid & 63;
    int node = (gid >> 6) * 2 + (lane >> 5);
    float s = layer_body(packed, xin, (__half*)nullptr, node, lane, false);
    if ((lane & 31) == 0) {
        float tot = sum1[node] + sum2[node] + 3.0f * s - 17.0f;
        rt4f[node * 16 + 12] = 1.0f / (1.0f + __expf(-tot));
    }
}

__global__ void wavg_kernel(const int* __restrict__ knn_src,
                            const float4* __restrict__ rt4,
                            const float* __restrict__ pos0,
                            float* __restrict__ out) {
    int gid = blockIdx.x * blockDim.x + threadIdx.x;
    int lane = gid & 63;
    int t = (gid >> 6) * 16 + (lane >> 2);
    if (t >= N_PTS) return;
    wavg_body(t, lane, knn_src, rt4, pos0, out);
}

extern "C" void kernel_launch(void* const* d_in, const int* in_sizes, int n_in,
                              void* d_out, int out_size, void* d_ws, size_t ws_size,
                              hipStream_t stream) {
    const float* x0 = (const float*)d_in[0];
    const float* pos0 = (const float*)d_in[1];
    const float* R0 = (const float*)d_in[2];
    const float* t0 = (const float*)d_in[3];
    const int* assign01 = (const int*)d_in[4];
    const int* radius_src = (const int*)d_in[5];
    const int* knn_src = (const int*)d_in[7];

    char* ws = (char*)d_ws;
    unsigned int* packed = (unsigned int*)ws;                  // @0       6,400,000 B
    __half* mA = (__half*)(ws + 6400000);                      // @6.4M    6,400,000 B
    __half* mB = (__half*)(ws + 12800000);                     // @12.8M   6,400,000 B
    float4* geo = (float4*)(ws + 19200000);                    // @19.2M   1,600,000 B
    float4* rt4 = (float4*)(ws + 20800000);                    // @20.8M   3,200,000 B
    float* sum1 = (float*)(ws + 24000000);
    float* sum2 = (float*)(ws + 24200000);
    float* out = (float*)d_out;

    void* args[] = {(void*)&x0, (void*)&pos0, (void*)&R0, (void*)&t0,
                    (void*)&assign01, (void*)&radius_src, (void*)&knn_src,
                    (void*)&packed, (void*)&mA, (void*)&mB, (void*)&geo,
                    (void*)&rt4, (void*)&sum1, (void*)&sum2, (void*)&out};

    hipError_t e = hipLaunchCooperativeKernel((const void*)fused_kernel, dim3(1024),
                                              dim3(NTHREADS), args, 0, stream);
    if (e != hipSuccess)
        e = hipLaunchCooperativeKernel((const void*)fused_kernel, dim3(512),
                                       dim3(NTHREADS), args, 0, stream);
    if (e != hipSuccess) {
        // Fallback: known-good 5-kernel path (R9).
        pack_tables_kernel<<<(N_PTS + 255) / 256, 256, 0, stream>>>(
            pos0, x0, assign01, R0, t0, geo, rt4);
        ew_layer1_kernel<<<N_PTS / 16, 256, 0, stream>>>(
            geo, R0, t0, radius_src, packed, mA, sum1);
        layer_pk_kernel<<<N_PTS / 8, 256, 0, stream>>>(
            packed, mA, mB, sum2);
        layer3_conf_pk_kernel<<<N_PTS / 8, 256, 0, stream>>>(
            packed, mB, sum1, sum2, (float*)rt4);
        wavg_kernel<<<(N_PTS * 4 + 255) / 256, 256, 0, stream>>>(
            knn_src, rt4, pos0, out);
    }
}

// Round 12
// 136.665 us; speedup vs baseline: 4.4196x; 4.4196x over previous
//
#include <hip/hip_runtime.h>
#include <hip/hip_fp16.h>
#include <math.h>

#define N_PTS 50000
#define C_DIM 64
#define K_RAD 32
#define K_KNN 10
#define E_RAD (N_PTS * K_RAD)

// ROCm hip_fp16.h has no __hmax2; emit packed fp16 max directly.
__device__ inline __half2 hmax2(__half2 a, __half2 b) {
    __half2 d;
    asm("v_pk_max_f16 %0, %1, %2" : "=v"(d) : "v"(a), "v"(b));
    return d;
}

__device__ inline __half2 shfl_xor_h2(__half2 v, int mask) {
    int i = *(int*)&v;
    int r = __shfl_xor(i, mask);
    return *(__half2*)&r;
}

// ---------------- K0: pack geo table only ----------------
// geo[i] = 2 x float4 (32 B): {pos0.xyz, x0.x}, {x0.y, x0.z, assign_bits, 0}
// (rt4 packing moved into ew_layer1, which already stages R0/t0 in LDS.)
__global__ void pack_tables_kernel(const float* __restrict__ pos0,
                                   const float* __restrict__ x0,
                                   const int* __restrict__ assign,
                                   float4* __restrict__ geo) {
    int i = blockIdx.x * blockDim.x + threadIdx.x;
    if (i >= N_PTS) return;
    geo[i * 2 + 0] = make_float4(pos0[3 * i], pos0[3 * i + 1], pos0[3 * i + 2], x0[3 * i]);
    geo[i * 2 + 1] = make_float4(x0[3 * i + 1], x0[3 * i + 2], __int_as_float(assign[i]), 0.0f);
}

// ---------------- K2: fused edge-weight + layer 1 + rt4 pack ----------
// 16 nodes/block (exact: 3125 blocks), 4 nodes/wave, 2 edges/lane.
// Also packs rt4[i] = {R0..3},{R4..7},{R8,t.xyz},{conf(K4),-} (64 B rows)
// for its own 16 nodes from the LDS-staged R/t (48 coalesced float4 stores).
__global__ void ew_layer1_kernel(const float4* __restrict__ geo,
                                 const float* __restrict__ R0,
                                 const float* __restrict__ t0,
                                 const int* __restrict__ src,
                                 unsigned int* __restrict__ packed,
                                 __half* __restrict__ m1,
                                 float* __restrict__ sum1,
                                 float4* __restrict__ rt4) {
    __shared__ int lm[16][C_DIM];     // 4 KB block max array
    __shared__ float ldsR[16 * 9];
    __shared__ float ldsT[16 * 3];
    int tid = threadIdx.x;
    int blk = blockIdx.x;
    ((int*)lm)[tid] = 0;
    ((int*)lm)[tid + 256] = 0;
    ((int*)lm)[tid + 512] = 0;
    ((int*)lm)[tid + 768] = 0;
    if (tid < 144) ldsR[tid] = R0[blk * 144 + tid];
    if (tid < 48) ldsT[tid] = t0[blk * 48 + tid];
    int nl = tid >> 4;                // local node 0..15
    int ng = blk * 16 + nl;           // global node
    int e0 = tid & 15, e1 = e0 + 16;
    int s0 = src[ng * K_RAD + e0];
    int s1 = src[ng * K_RAD + e1];
    float4 g0a = geo[s0 * 2 + 0];
    float4 g0b = geo[s0 * 2 + 1];
    float4 g1a = geo[s1 * 2 + 0];
    float4 g1b = geo[s1 * 2 + 1];
    __syncthreads();
    // rt4 pack for this block's 16 nodes (threads 0..47, one float4 each)
    if (tid < 48) {
        int n = tid / 3, slot = tid % 3;
        const float* R = ldsR + n * 9;
        const float* T = ldsT + n * 3;
        float4 q;
        if (slot == 0) q = make_float4(R[0], R[1], R[2], R[3]);
        else if (slot == 1) q = make_float4(R[4], R[5], R[6], R[7]);
        else q = make_float4(R[8], T[0], T[1], T[2]);
        rt4[(blk * 16 + n) * 4 + slot] = q;
    }
    const float* R = ldsR + nl * 9;
    const float* T = ldsT + nl * 3;
    float r0 = R[0] * g0a.x + R[1] * g0a.y + R[2] * g0a.z + T[0] - g0a.w;
    float r1 = R[3] * g0a.x + R[4] * g0a.y + R[5] * g0a.z + T[1] - g0b.x;
    float r2 = R[6] * g0a.x + R[7] * g0a.y + R[8] * g0a.z + T[2] - g0b.y;
    float d0 = r0 * r0 + r1 * r1 + r2 * r2;
    float w0 = 1.0f / (1.0f + __expf(d0 - 0.01f));
    float u0 = R[0] * g1a.x + R[1] * g1a.y + R[2] * g1a.z + T[0] - g1a.w;
    float u1 = R[3] * g1a.x + R[4] * g1a.y + R[5] * g1a.z + T[1] - g1b.x;
    float u2 = R[6] * g1a.x + R[7] * g1a.y + R[8] * g1a.z + T[2] - g1b.y;
    float d1 = u0 * u0 + u1 * u1 + u2 * u2;
    float w1 = 1.0f / (1.0f + __expf(d1 - 0.01f));
    packed[ng * K_RAD + e0] =
        ((unsigned int)s0 << 16) | (unsigned int)__half_as_ushort(__float2half_rn(w0));
    packed[ng * K_RAD + e1] =
        ((unsigned int)s1 << 16) | (unsigned int)__half_as_ushort(__float2half_rn(w1));
    atomicMax(&lm[nl][__float_as_int(g0b.z)], __float_as_int(w0));
    atomicMax(&lm[nl][__float_as_int(g1b.z)], __float_as_int(w1));
    __syncthreads();
    // m1 + sum1: thread -> node tid>>4, channel quad (tid&15)*4
    int c0 = (tid & 15) * 4;
    float v0 = __int_as_float(lm[nl][c0 + 0]);
    float v1 = __int_as_float(lm[nl][c0 + 1]);
    float v2 = __int_as_float(lm[nl][c0 + 2]);
    float v3 = __int_as_float(lm[nl][c0 + 3]);
    __half2 h01 = __floats2half2_rn(v0, v1);
    __half2 h23 = __floats2half2_rn(v2, v3);
    uint2 uo = make_uint2(*(unsigned int*)&h01, *(unsigned int*)&h23);
    *(uint2*)(m1 + ng * C_DIM + c0) = uo;
    float s = v0 + v1 + v2 + v3;
    s += __shfl_down(s, 8);
    s += __shfl_down(s, 4);
    s += __shfl_down(s, 2);
    s += __shfl_down(s, 1);
    if ((tid & 15) == 0) sum1[ng] = s;
}

// ---------------- K3: fp16 layer, 2 nodes/wave ----------------
// lane = (nl = lane>>5, eslot = (lane>>3)&3, cpos = lane&7).
// 8 pe-words preloaded (2 x uint4); 8 independent 16B gathers in flight.
__global__ void layer_pk_kernel(const unsigned int* __restrict__ packed,
                                const __half* __restrict__ xin,
                                __half* __restrict__ xout,
                                float* __restrict__ sum_out) {
    int gid = blockIdx.x * blockDim.x + threadIdx.x;
    int lane = gid & 63;
    int node = (gid >> 6) * 2 + (lane >> 5);   // exact: 25000 waves
    int eslot = (lane >> 3) & 3;
    int cpos = lane & 7;
    const uint4* pk4 = (const uint4*)(packed + node * K_RAD + eslot * 8);
    uint4 q0 = pk4[0], q1 = pk4[1];
    unsigned int pes[8] = {q0.x, q0.y, q0.z, q0.w, q1.x, q1.y, q1.z, q1.w};
    __half2 a0 = __float2half2_rn(0.0f), a1 = a0, a2 = a0, a3 = a0;
#pragma unroll
    for (int p = 0; p < 8; ++p) {
        unsigned int pe = pes[p];
        float4 f = *(const float4*)(xin + (pe >> 16) * C_DIM + cpos * 8);
        __half2* h = (__half2*)&f;
        __half2 w2 = __half2half2(__ushort_as_half((unsigned short)(pe & 0xffffu)));
        a0 = hmax2(a0, __hmul2(w2, h[0]));
        a1 = hmax2(a1, __hmul2(w2, h[1]));
        a2 = hmax2(a2, __hmul2(w2, h[2]));
        a3 = hmax2(a3, __hmul2(w2, h[3]));
    }
#pragma unroll
    for (int off = 8; off <= 16; off <<= 1) {   // max across 4 eslots
        a0 = hmax2(a0, shfl_xor_h2(a0, off));
        a1 = hmax2(a1, shfl_xor_h2(a1, off));
        a2 = hmax2(a2, shfl_xor_h2(a2, off));
        a3 = hmax2(a3, shfl_xor_h2(a3, off));
    }
    if (eslot == 0) {
        float4 o;
        __half2* oh = (__half2*)&o;
        oh[0] = a0; oh[1] = a1; oh[2] = a2; oh[3] = a3;
        ((float4*)(xout + node * C_DIM))[cpos] = o;
    }
    float2 v0 = __half22float2(a0), v1 = __half22float2(a1);
    float2 v2 = __half22float2(a2), v3 = __half22float2(a3);
    float s = v0.x + v0.y + v1.x + v1.y + v2.x + v2.y + v3.x + v3.y;
    s += __shfl_xor(s, 1);
    s += __shfl_xor(s, 2);
    s += __shfl_xor(s, 4);
    if ((lane & 31) == 0) sum_out[node] = s;
}

// ---------------- K4: layer 3 + fused confidence, 2 nodes/wave ----------
// m3 == m4 == m5  =>  conf = sigmoid(sum1 + sum2 + 3*sum3 - 17)
// conf written into rt4[node*4+3].x for K5.
__global__ void layer3_conf_pk_kernel(const unsigned int* __restrict__ packed,
                                      const __half* __restrict__ xin,
                                      const float* __restrict__ sum1,
                                      const float* __restrict__ sum2,
                                      float* __restrict__ rt4f) {
    int gid = blockIdx.x * blockDim.x + threadIdx.x;
    int lane = gid & 63;
    int node = (gid >> 6) * 2 + (lane >> 5);
    int eslot = (lane >> 3) & 3;
    int cpos = lane & 7;
    const uint4* pk4 = (const uint4*)(packed + node * K_RAD + eslot * 8);
    uint4 q0 = pk4[0], q1 = pk4[1];
    unsigned int pes[8] = {q0.x, q0.y, q0.z, q0.w, q1.x, q1.y, q1.z, q1.w};
    __half2 a0 = __float2half2_rn(0.0f), a1 = a0, a2 = a0, a3 = a0;
#pragma unroll
    for (int p = 0; p < 8; ++p) {
        unsigned int pe = pes[p];
        float4 f = *(const float4*)(xin + (pe >> 16) * C_DIM + cpos * 8);
        __half2* h = (__half2*)&f;
        __half2 w2 = __half2half2(__ushort_as_half((unsigned short)(pe & 0xffffu)));
        a0 = hmax2(a0, __hmul2(w2, h[0]));
        a1 = hmax2(a1, __hmul2(w2, h[1]));
        a2 = hmax2(a2, __hmul2(w2, h[2]));
        a3 = hmax2(a3, __hmul2(w2, h[3]));
    }
#pragma unroll
    for (int off = 8; off <= 16; off <<= 1) {
        a0 = hmax2(a0, shfl_xor_h2(a0, off));
        a1 = hmax2(a1, shfl_xor_h2(a1, off));
        a2 = hmax2(a2, shfl_xor_h2(a2, off));
        a3 = hmax2(a3, shfl_xor_h2(a3, off));
    }
    float2 v0 = __half22float2(a0), v1 = __half22float2(a1);
    float2 v2 = __half22float2(a2), v3 = __half22float2(a3);
    float s = v0.x + v0.y + v1.x + v1.y + v2.x + v2.y + v3.x + v3.y;
    s += __shfl_xor(s, 1);
    s += __shfl_xor(s, 2);
    s += __shfl_xor(s, 4);
    if ((lane & 31) == 0) {
        float tot = sum1[node] + sum2[node] + 3.0f * s - 17.0f;
        rt4f[node * 16 + 12] = 1.0f / (1.0f + __expf(-tot));
    }
}

// ---------------- K5: weighted average over knn + rigid transform --------
// 4 lanes per node (16 nodes/wave).
__global__ void wavg_kernel(const int* __restrict__ knn_src,
                            const float4* __restrict__ rt4,
                            const float* __restrict__ pos0,
                            float* __restrict__ out) {
    int gid = blockIdx.x * blockDim.x + threadIdx.x;
    int lane = gid & 63;
    int t = (gid >> 6) * 16 + (lane >> 2);
    int part = lane & 3;
    if (t >= N_PTS) return;
    float4 acc = make_float4(0.f, 0.f, 0.f, 0.f);
    for (int j = 0; j < K_KNN; ++j) {
        int s = knn_src[t * K_KNN + j];
        float4 q = rt4[s * 4 + part];      // part3: q.x = conf[s]
        float c = __shfl(q.x, lane | 3);
        if (part == 3) {
            acc.x += c;
        } else {
            acc.x += c * q.x; acc.y += c * q.y;
            acc.z += c * q.z; acc.w += c * q.w;
        }
    }
    float den = __shfl(acc.x, lane | 3) + 1e-8f;
    float inv = 1.0f / den;
    float4 sc = make_float4(acc.x * inv, acc.y * inv, acc.z * inv, acc.w * inv);
    int base = lane & ~3;
    float R3 = __shfl(sc.w, base + 0);
    float R6 = __shfl(sc.z, base + 1);
    float R7 = __shfl(sc.w, base + 1);
    float t0v = __shfl(sc.y, base + 2);
    float t1v = __shfl(sc.z, base + 2);
    float px = pos0[t * 3 + 0], py = pos0[t * 3 + 1], pz = pos0[t * 3 + 2];
    float* Rout = out + N_PTS * 3;
    float* tout = out + N_PTS * 12;
    if (part == 0) {
        out[t * 3 + 0] = sc.x * px + sc.y * py + sc.z * pz + t0v;
        Rout[t * 9 + 0] = sc.x; Rout[t * 9 + 1] = sc.y;
        Rout[t * 9 + 2] = sc.z; Rout[t * 9 + 3] = sc.w;
    } else if (part == 1) {
        out[t * 3 + 1] = R3 * px + sc.x * py + sc.y * pz + t1v;
        Rout[t * 9 + 4] = sc.x; Rout[t * 9 + 5] = sc.y;
        Rout[t * 9 + 6] = sc.z; Rout[t * 9 + 7] = sc.w;
    } else if (part == 2) {
        out[t * 3 + 2] = R6 * px + R7 * py + sc.x * pz + sc.w;
        Rout[t * 9 + 8] = sc.x;
        tout[t * 3 + 0] = sc.y; tout[t * 3 + 1] = sc.z; tout[t * 3 + 2] = sc.w;
    }
}

extern "C" void kernel_launch(void* const* d_in, const int* in_sizes, int n_in,
                              void* d_out, int out_size, void* d_ws, size_t ws_size,
                              hipStream_t stream) {
    const float* x0 = (const float*)d_in[0];
    const float* pos0 = (const float*)d_in[1];
    const float* R0 = (const float*)d_in[2];
    const float* t0 = (const float*)d_in[3];
    const int* assign01 = (const int*)d_in[4];
    const int* radius_src = (const int*)d_in[5];
    const int* knn_src = (const int*)d_in[7];

    // All tables 128-B aligned.
    char* ws = (char*)d_ws;
    unsigned int* packed = (unsigned int*)ws;                  // @0          6,400,000 B
    __half* mA = (__half*)(ws + 6400000);                      // @6.4M       6,400,000 B
    __half* mB = (__half*)(ws + 12800000);                     // @12.8M      6,400,000 B
    float4* geo = (float4*)(ws + 19200000);                    // @19.2M      1,600,000 B
    float4* rt4 = (float4*)(ws + 20800000);                    // @20.8M      3,200,000 B
    float* sum1 = (float*)(ws + 24000000);                     //   200,000 B
    float* sum2 = (float*)(ws + 24200000);                     //   200,000 B
    float* out = (float*)d_out;

    pack_tables_kernel<<<(N_PTS + 255) / 256, 256, 0, stream>>>(
        pos0, x0, assign01, geo);

    // 16 nodes/block, exact grid; also packs rt4 R/t rows
    ew_layer1_kernel<<<N_PTS / 16, 256, 0, stream>>>(
        geo, R0, t0, radius_src, packed, mA, sum1, rt4);

    // 2 nodes/wave, 8 nodes/block, exact grid
    layer_pk_kernel<<<N_PTS / 8, 256, 0, stream>>>(
        packed, mA, mB, sum2);

    layer3_conf_pk_kernel<<<N_PTS / 8, 256, 0, stream>>>(
        packed, mB, sum1, sum2, (float*)rt4);

    wavg_kernel<<<(N_PTS * 4 + 255) / 256, 256, 0, stream>>>(
        knn_src, rt4, pos0, out);
}